// Round 1
// 125.421 us; speedup vs baseline: 1.0315x; 1.0315x over previous
//
#include <hip/hip_runtime.h>

#define NIMG 16
#define H 512
#define W 512
#define HALF 7        // PATCH=15

// ---- fused-tile geometry ----
#define RT 64         // output rows per tile (full res)
#define CT 256        // output cols per tile (full res)
#define YROWS 78      // RT + 2*HALF
#define YCOLS 272     // CT + 16  (halo 8 each side, even so float2 stores align)
#define YSTR 276      // sY row stride (floats): %4==0 (float4 align), %32==20 (bank spread)
#define CROWS 46      // RT/2 + 2*HALF
#define CCOLS 142     // CT/2 + 2*HALF
#define CSTR 152      // sU/sV row stride (ushorts): byte stride 304 = 19*16 (uint4 align)

// bf16 helpers (RNE), bit-level.
static __device__ __forceinline__ unsigned short f2bf(float f) {
    unsigned u = __float_as_uint(f);
    u += 0x7FFFu + ((u >> 16) & 1u);
    return (unsigned short)(u >> 16);
}
static __device__ __forceinline__ float bf2f(unsigned short h) {
    return __uint_as_float(((unsigned)h) << 16);
}
static __device__ __forceinline__ float bflo(unsigned v) {
    return __uint_as_float(v << 16);
}
static __device__ __forceinline__ float bfhi(unsigned v) {
    return __uint_as_float(v & 0xFFFF0000u);
}

// ---------------------------------------------------------------------------
// Fused: diff -> YUV -> 2x2 pool -> 15x15 box (vbox in-place, hbox in regs)
// -> square -> per-block partial. One block per 64x256 output tile.
// Grid: 16 img * 8 row-tiles * 2 col-tiles = 256 blocks (1 per CU), 512 thr.
// LDS: fp32 dY[78][276] + bf16 dU/dV[46][152] = 111.4 KiB -> 1 block/CU.
// ---------------------------------------------------------------------------
__global__ __launch_bounds__(512) void fused_loss_kernel(
        const float* __restrict__ in, const float* __restrict__ tgt,
        float invY, float invC, float* __restrict__ partials) {
    __shared__ float sY[YROWS * YSTR];
    __shared__ unsigned short sU[CROWS * CSTR];
    __shared__ unsigned short sV[CROWS * CSTR];
    __shared__ float part[8];

    const int tid = threadIdx.x;
    const int b = blockIdx.x;
    const int n  = b >> 4;
    const int rt = (b >> 1) & 7;
    const int ct = b & 1;
    const int r0 = rt << 6;   // first output row (full res)
    const int c0 = ct << 8;   // first output col (full res)

    const size_t plane = (size_t)H * W;
    const float* pi = in  + (size_t)n * 3 * plane;
    const float* pt = tgt + (size_t)n * 3 * plane;

    // ---- Stage 1: 2x2 input patches -> dY (fp32, luma extent) + pooled dU/dV (bf16)
    // Patch grid: 46 chroma rows x 144 chroma cols (142 used). Patches are
    // 2-aligned, image dims even -> each patch fully in- or out-of-image.
    // Out-of-image patches write zeros (= the conv's zero padding).
#pragma unroll 2
    for (int i = tid; i < CROWS * 144; i += 512) {
        const int pr = i / 144;
        const int pc = i - pr * 144;
        const int yy = r0 - 14 + 2 * pr;   // full-res row of patch top
        const int xx = c0 - 14 + 2 * pc;   // full-res col of patch left

        float dr00=0.f,dr01=0.f,dr10=0.f,dr11=0.f;
        float dg00=0.f,dg01=0.f,dg10=0.f,dg11=0.f;
        float db00=0.f,db01=0.f,db10=0.f,db11=0.f;

        if ((unsigned)yy < H && (unsigned)xx < W && pc < CCOLS) {
            const int off = yy * W + xx;
            const float2 ir0 = *(const float2*)(pi + off);
            const float2 ir1 = *(const float2*)(pi + off + W);
            const float2 ig0 = *(const float2*)(pi + plane + off);
            const float2 ig1 = *(const float2*)(pi + plane + off + W);
            const float2 ib0 = *(const float2*)(pi + 2 * plane + off);
            const float2 ib1 = *(const float2*)(pi + 2 * plane + off + W);
            const float2 tr0 = *(const float2*)(pt + off);
            const float2 tr1 = *(const float2*)(pt + off + W);
            const float2 tg0 = *(const float2*)(pt + plane + off);
            const float2 tg1 = *(const float2*)(pt + plane + off + W);
            const float2 tb0 = *(const float2*)(pt + 2 * plane + off);
            const float2 tb1 = *(const float2*)(pt + 2 * plane + off + W);
            dr00 = ir0.x - tr0.x; dr01 = ir0.y - tr0.y;
            dr10 = ir1.x - tr1.x; dr11 = ir1.y - tr1.y;
            dg00 = ig0.x - tg0.x; dg01 = ig0.y - tg0.y;
            dg10 = ig1.x - tg1.x; dg11 = ig1.y - tg1.y;
            db00 = ib0.x - tb0.x; db01 = ib0.y - tb0.y;
            db10 = ib1.x - tb1.x; db11 = ib1.y - tb1.y;
        }

        // luma diffs (4 pixels)
        const float y00 = 0.299f * dr00 + 0.587f * dg00 + 0.114f * db00;
        const float y01 = 0.299f * dr01 + 0.587f * dg01 + 0.114f * db01;
        const float y10 = 0.299f * dr10 + 0.587f * dg10 + 0.114f * db10;
        const float y11 = 0.299f * dr11 + 0.587f * dg11 + 0.114f * db11;

        // sY col 0 <-> global col c0-8 ; sY row 0 <-> global row r0-7
        const int ly0 = 2 * pr - 7;       // odd row of the pair
        const int lx0 = 2 * pc - 6;       // even -> float2-aligned
        if ((unsigned)lx0 < YCOLS) {
            if ((unsigned)ly0 < YROWS)
                *(float2*)&sY[ly0 * YSTR + lx0] = make_float2(y00, y01);
            if ((unsigned)(ly0 + 1) < YROWS)
                *(float2*)&sY[(ly0 + 1) * YSTR + lx0] = make_float2(y10, y11);
        }

        // pooled chroma diffs (+128 cancels in input-target)
        const float sr = dr00 + dr01 + dr10 + dr11;
        const float sg = dg00 + dg01 + dg10 + dg11;
        const float sb = db00 + db01 + db10 + db11;
        sU[pr * CSTR + pc] = f2bf((-0.169f * sr - 0.331f * sg + 0.5f  * sb) * 0.25f);
        sV[pr * CSTR + pc] = f2bf(( 0.5f   * sr - 0.46f  * sg - 0.04f * sb) * 0.25f);
    }
    __syncthreads();

    // ---- Phase A: vertical 15-tap box, in-place (thread-private columns).
    // Row y of the window dies exactly when output y is produced -> overwrite.
    for (int t = tid; t < YCOLS + 2 * CCOLS; t += 512) {   // 272 + 284 = 556 tasks
        if (t < YCOLS) {
            const int j = t;
            float s = 0.f;
#pragma unroll
            for (int r = 0; r < 14; ++r) s += sY[r * YSTR + j];
#pragma unroll
            for (int y = 0; y < RT; ++y) {
                s += sY[(y + 14) * YSTR + j];
                const float o = s;
                s -= sY[y * YSTR + j];
                sY[y * YSTR + j] = o;
            }
        } else {
            const int jj = t - YCOLS;
            unsigned short* sp = (jj < CCOLS) ? sU : sV;
            const int j = (jj < CCOLS) ? jj : jj - CCOLS;
            float s = 0.f;
#pragma unroll
            for (int r = 0; r < 14; ++r) s += bf2f(sp[r * CSTR + j]);
#pragma unroll
            for (int y = 0; y < RT / 2; ++y) {
                s += bf2f(sp[(y + 14) * CSTR + j]);
                const float o = s;
                s -= bf2f(sp[y * CSTR + j]);
                sp[y * CSTR + j] = f2bf(o);
            }
        }
    }
    __syncthreads();

    // ---- Phase B: horizontal 15-tap box + square, sliding in registers.
    float accY = 0.f, accC = 0.f;
    const int wv = tid >> 6, lane = tid & 63;

    {   // luma: wave wv owns 32-col segment, lane = output row (0..63)
        float wn[48];
        const int base = lane * YSTR + (wv << 5);
#pragma unroll
        for (int j = 0; j < 12; ++j)
            *(float4*)&wn[4 * j] = *(const float4*)&sY[base + 4 * j];
        // out col xo = 32*wv + k  <->  window wn[k+1 .. k+15]
        float s = 0.f;
#pragma unroll
        for (int j = 1; j <= 14; ++j) s += wn[j];
#pragma unroll
        for (int k = 0; k < 32; ++k) {
            s += wn[15 + k];
            accY += s * s;
            s -= wn[1 + k];
        }
    }

    {   // chroma: lane>>5 picks U/V plane, lane&31 = row, wave = 16-col segment
        const int pl = lane >> 5, y = lane & 31;
        const unsigned short* sp = pl ? sV : sU;
        const int base = y * CSTR + (wv << 4);
        float wn[32];
#pragma unroll
        for (int j = 0; j < 4; ++j) {
            const uint4 v = *(const uint4*)&sp[base + 8 * j];
            wn[8 * j + 0] = bflo(v.x); wn[8 * j + 1] = bfhi(v.x);
            wn[8 * j + 2] = bflo(v.y); wn[8 * j + 3] = bfhi(v.y);
            wn[8 * j + 4] = bflo(v.z); wn[8 * j + 5] = bfhi(v.z);
            wn[8 * j + 6] = bflo(v.w); wn[8 * j + 7] = bfhi(v.w);
        }
        // out col xo = 16*wv + k  <->  window wn[k .. k+14]
        float s = 0.f;
#pragma unroll
        for (int j = 0; j < 14; ++j) s += wn[j];
#pragma unroll
        for (int k = 0; k < 16; ++k) {
            s += wn[14 + k];
            accC += s * s;
            s -= wn[k];
        }
    }

    // ---- block reduction -> one partial per block
    float v = accY * invY + accC * invC;
    for (int o = 32; o > 0; o >>= 1) v += __shfl_down(v, o, 64);
    if (lane == 0) part[wv] = v;
    __syncthreads();
    if (tid == 0) {
        float s = 0.f;
#pragma unroll
        for (int j = 0; j < 8; ++j) s += part[j];
        partials[b] = s;
    }
}

// ---------------------------------------------------------------------------
// Final: single-block sum of 256 partials -> out[0].
// ---------------------------------------------------------------------------
__global__ void final_reduce_kernel(const float* __restrict__ partials, int n,
                                    float* __restrict__ out) {
    float s = 0.f;
    for (int i = threadIdx.x; i < n; i += 256) s += partials[i];
    for (int o = 32; o > 0; o >>= 1) s += __shfl_down(s, o, 64);
    __shared__ float part[4];
    const int lane = threadIdx.x & 63, wid = threadIdx.x >> 6;
    if (lane == 0) part[wid] = s;
    __syncthreads();
    if (threadIdx.x == 0)
        *out = part[0] + part[1] + part[2] + part[3];
}

extern "C" void kernel_launch(void* const* d_in, const int* in_sizes, int n_in,
                              void* d_out, int out_size, void* d_ws, size_t ws_size,
                              hipStream_t stream) {
    const float* input  = (const float*)d_in[0];
    const float* target = (const float*)d_in[1];
    float* out = (float*)d_out;
    float* partials = (float*)d_ws;   // 256 floats

    const float invY = 1.0f / (float)((size_t)NIMG * H * W);            // 1/4194304
    const float invC = 1.0f / (float)((size_t)NIMG * (H/2) * (W/2));    // 1/1048576

    fused_loss_kernel<<<NIMG * 8 * 2, 512, 0, stream>>>(input, target, invY, invC, partials);
    final_reduce_kernel<<<1, 256, 0, stream>>>(partials, NIMG * 8 * 2, out);
}